// Round 5
// baseline (616.314 us; speedup 1.0000x reference)
//
#include <hip/hip_runtime.h>
#include <math.h>

#define LEAKY(x) ((x) > 0.f ? (x) : 0.01f * (x))

__device__ __forceinline__ void fma4(float4& acc, float s, const float4& v) {
    acc.x += s * v.x; acc.y += s * v.y; acc.z += s * v.z; acc.w += s * v.w;
}

__global__ void zero_i32(int* p, int n) {
    int i = blockIdx.x * 256 + threadIdx.x;
    if (i < n) p[i] = 0;
}

__global__ void count_kernel(const int* __restrict__ dst, int* __restrict__ counts, int E) {
    int e = blockIdx.x * 256 + threadIdx.x;
    if (e < E) atomicAdd(&counts[dst[e]], 1);
}

// Stage A: per-block (2048 elems) local exclusive scan into row_ptr, block sums
// into bsum, and dis = rsqrt(count+1) folded in.
__global__ __launch_bounds__(256) void scanA(const int* __restrict__ counts,
                                             int* __restrict__ row_ptr,
                                             int* __restrict__ bsum,
                                             float* __restrict__ dis, int n) {
    __shared__ int sm[256];
    int base = blockIdx.x * 2048 + threadIdx.x * 8;
    int v[8];
    int s = 0;
#pragma unroll
    for (int j = 0; j < 8; ++j) {
        int i = base + j;
        int c = (i < n) ? counts[i] : 0;
        v[j] = c;
        s += c;
        if (i < n) dis[i] = rsqrtf((float)(c + 1));  // +1: self-loop
    }
    sm[threadIdx.x] = s;
    __syncthreads();
    for (int off = 1; off < 256; off <<= 1) {
        int t = (threadIdx.x >= off) ? sm[threadIdx.x - off] : 0;
        __syncthreads();
        sm[threadIdx.x] += t;
        __syncthreads();
    }
    int excl = sm[threadIdx.x] - s;
#pragma unroll
    for (int j = 0; j < 8; ++j) {
        int i = base + j;
        if (i < n) row_ptr[i] = excl;
        excl += v[j];
    }
    if (threadIdx.x == 255) bsum[blockIdx.x] = sm[255];
}

// Stage B: single-wave exclusive scan of block sums (nb <= 64).
__global__ __launch_bounds__(64) void scanB(int* __restrict__ bsum, int nb) {
    __shared__ int sm[64];
    int v = (threadIdx.x < nb) ? bsum[threadIdx.x] : 0;
    sm[threadIdx.x] = v;
    __syncthreads();
    for (int off = 1; off < 64; off <<= 1) {
        int t = (threadIdx.x >= off) ? sm[threadIdx.x - off] : 0;
        __syncthreads();
        sm[threadIdx.x] += t;
        __syncthreads();
    }
    if (threadIdx.x < nb) bsum[threadIdx.x] = sm[threadIdx.x] - v;
}

// Stage C: add block offsets, copy to cursor, write row_ptr[n] = E.
__global__ void scanC(int* __restrict__ row_ptr, int* __restrict__ cursor,
                      const int* __restrict__ bsum, int n, int E) {
    int i = blockIdx.x * 256 + threadIdx.x;
    if (i < n) {
        int v = row_ptr[i] + bsum[i >> 11];
        row_ptr[i] = v;
        cursor[i] = v;
    }
    if (i == 0) row_ptr[n] = E;
}

// CSR fill; stores (src, dis[src]) packed so agg does a single 8B load per edge.
__global__ void fill_kernel(const int* __restrict__ src, const int* __restrict__ dst,
                            int* __restrict__ cursor, const float* __restrict__ dis,
                            uint2* __restrict__ edge_sw, int E) {
    int e = blockIdx.x * 256 + threadIdx.x;
    if (e < E) {
        int s = src[e];
        int pos = atomicAdd(&cursor[dst[e]], 1);
        edge_sw[pos] = make_uint2((unsigned)s, __float_as_uint(dis[s]));
    }
}

// Fused GCN layer: Y = leaky( agg(X) @ W + b ) over a 32-node tile.
//  Phase 1 (gather): 32 nodes x LPN lanes, NF4PL float4 chunks/lane.
//    agg_i = dis_i * ( sum_{s in in(i)} dis_s * X_s  +  dis_i * X_i )
//    Edge range staged once into LDS (contiguous in CSR); result -> padded LDS
//    A-tile (stride K+4 floats, breaks the 96-stride 8-way b128 bank conflict).
//  Phase 2 (GEMM): thread (r=tid/8, c=tid%8) computes out f4-cols {c,c+8,c+16}
//    for row r; W read from global (wave-broadcast, L1/L2-resident).
template <int LPN, int NF4PL, int K>
__global__ __launch_bounds__(256) void layer_kernel(const float* __restrict__ X,
                                                    const float* __restrict__ dis,
                                                    const int* __restrict__ row_ptr,
                                                    const uint2* __restrict__ edge_sw,
                                                    const float* __restrict__ W,
                                                    const float* __restrict__ b,
                                                    float* __restrict__ Y, int n) {
    constexpr int KQ_in = LPN * NF4PL;   // input f4 per node
    static_assert(KQ_in * 4 == K, "lanes*chunks must cover K");
    constexpr int KP = K + 4;            // padded LDS row stride (floats)
    constexpr int ECAP = 1024;           // avg edges per 32-node tile ~512
    __shared__ uint2 eb[ECAP];
    __shared__ __align__(16) float Als[32 * KP];

    int i0 = blockIdx.x * 32;
    int iend = min(i0 + 32, n);
    int e0 = row_ptr[i0];
    int stage = min(row_ptr[iend] - e0, ECAP);
    for (int idx = threadIdx.x; idx < stage; idx += 256)
        eb[idx] = edge_sw[e0 + idx];
    __syncthreads();

    int tid = threadIdx.x;
    if (tid < 32 * LPN) {
        int r = tid / LPN, c = tid % LPN;
        int i = i0 + r;
        if (i < n) {
            const float4* X4 = (const float4*)X;
            float di = dis[i];
            size_t base = (size_t)i * KQ_in + c * NF4PL;
            float4 acc[NF4PL];
#pragma unroll
            for (int j = 0; j < NF4PL; ++j) {
                float4 xv = X4[base + j];
                acc[j] = make_float4(di * xv.x, di * xv.y, di * xv.z, di * xv.w);
            }
            int re0 = row_ptr[i], re1 = row_ptr[i + 1];
#pragma unroll 2
            for (int e = re0; e < re1; ++e) {
                int le = e - e0;
                uint2 ew = (le < stage) ? eb[le] : edge_sw[e];
                float ds = __uint_as_float(ew.y);
                size_t sb = (size_t)(int)ew.x * KQ_in + c * NF4PL;
#pragma unroll
                for (int j = 0; j < NF4PL; ++j) {
                    float4 xs = X4[sb + j];
                    fma4(acc[j], ds, xs);
                }
            }
#pragma unroll
            for (int j = 0; j < NF4PL; ++j) {
                float4 o = make_float4(di * acc[j].x, di * acc[j].y,
                                       di * acc[j].z, di * acc[j].w);
                *(float4*)&Als[r * KP + (c * NF4PL + j) * 4] = o;
            }
        } else {
#pragma unroll
            for (int j = 0; j < NF4PL; ++j)
                *(float4*)&Als[r * KP + (c * NF4PL + j) * 4] =
                    make_float4(0.f, 0.f, 0.f, 0.f);
        }
    }
    __syncthreads();

    // GEMM phase
    int r = tid >> 3, c = tid & 7;
    const float4* W4 = (const float4*)W;  // W4[k*24 + fq]
    float4 a0 = ((const float4*)b)[c];
    float4 a1 = ((const float4*)b)[c + 8];
    float4 a2 = ((const float4*)b)[c + 16];
    for (int kc = 0; kc < K; kc += 4) {
        float4 a = *(const float4*)&Als[r * KP + kc];
        const float* ap = &a.x;
#pragma unroll
        for (int kk = 0; kk < 4; ++kk) {
            float av = ap[kk];
            float4 w0 = W4[(size_t)(kc + kk) * 24 + c];
            float4 w1 = W4[(size_t)(kc + kk) * 24 + c + 8];
            float4 w2 = W4[(size_t)(kc + kk) * 24 + c + 16];
            fma4(a0, av, w0);
            fma4(a1, av, w1);
            fma4(a2, av, w2);
        }
    }
    int i = i0 + r;
    if (i < n) {
        float4 o0, o1, o2;
        o0.x = LEAKY(a0.x); o0.y = LEAKY(a0.y); o0.z = LEAKY(a0.z); o0.w = LEAKY(a0.w);
        o1.x = LEAKY(a1.x); o1.y = LEAKY(a1.y); o1.z = LEAKY(a1.z); o1.w = LEAKY(a1.w);
        o2.x = LEAKY(a2.x); o2.y = LEAKY(a2.y); o2.z = LEAKY(a2.z); o2.w = LEAKY(a2.w);
        float4* Y4 = (float4*)Y;
        Y4[(size_t)i * 24 + c] = o0;
        Y4[(size_t)i * 24 + c + 8] = o1;
        Y4[(size_t)i * 24 + c + 16] = o2;
    }
}

__device__ __forceinline__ int lower_bound(const int* b, int n, int v) {
    int lo = 0, hi = n;
    while (lo < hi) {
        int m = (lo + hi) >> 1;
        if (b[m] < v) lo = m + 1; else hi = m;
    }
    return lo;
}

// grid = G*8, block = 96. Chunked per-graph partial max/sum.
__global__ void pool_partial(const float* __restrict__ X, const int* __restrict__ batch,
                             float* __restrict__ pmax, float* __restrict__ psum, int n) {
    int g = blockIdx.x / 8, ch = blockIdx.x % 8;
    int f = threadIdx.x;
    int s = lower_bound(batch, n, g), e = lower_bound(batch, n, g + 1);
    int len = e - s;
    int cs = s + (int)((long)len * ch / 8);
    int ce = s + (int)((long)len * (ch + 1) / 8);
    float mx = -INFINITY, sm = 0.f;
    for (int i = cs; i < ce; ++i) {
        float v = X[(size_t)i * 96 + f];
        mx = fmaxf(mx, v);
        sm += v;
    }
    pmax[(size_t)blockIdx.x * 96 + f] = mx;
    psum[(size_t)blockIdx.x * 96 + f] = sm;
}

__global__ void pool_reduce(const float* __restrict__ pmax, const float* __restrict__ psum,
                            const int* __restrict__ batch, float* __restrict__ pooled, int n) {
    int g = blockIdx.x, f = threadIdx.x;
    float mx = -INFINITY, sm = 0.f;
    for (int c = 0; c < 8; ++c) {
        mx = fmaxf(mx, pmax[(size_t)(g * 8 + c) * 96 + f]);
        sm += psum[(size_t)(g * 8 + c) * 96 + f];
    }
    int s = lower_bound(batch, n, g), e = lower_bound(batch, n, g + 1);
    float cnt = fmaxf((float)(e - s), 1.f);
    pooled[g * 192 + f] = mx;
    pooled[g * 192 + 96 + f] = sm / cnt;
}

// out[g] = leaky(pooled[g]@Wo1 + bo1) @ Wo2 + bo2
__global__ void mlp_kernel(const float* __restrict__ pooled, const float* __restrict__ Wo1,
                           const float* __restrict__ bo1, const float* __restrict__ Wo2,
                           const float* __restrict__ bo2, float* __restrict__ out) {
    __shared__ float sh[96];
    int g = blockIdx.x, f = threadIdx.x;
    float acc = bo1[f];
    for (int k = 0; k < 192; ++k) acc += pooled[g * 192 + k] * Wo1[k * 96 + f];
    float a = LEAKY(acc);
    sh[f] = a * Wo2[f];
    __syncthreads();
    if (f == 0) {
        float sacc = 0.f;
        for (int k = 0; k < 96; ++k) sacc += sh[k];
        out[g] = sacc + bo2[0];
    }
}

extern "C" void kernel_launch(void* const* d_in, const int* in_sizes, int n_in,
                              void* d_out, int out_size, void* d_ws, size_t ws_size,
                              hipStream_t stream) {
    const float* x      = (const float*)d_in[0];
    const int*   eidx   = (const int*)d_in[1];
    const int*   batch  = (const int*)d_in[2];
    const float* W_init = (const float*)d_in[3];
    const float* b_init = (const float*)d_in[4];
    const float* W1 = (const float*)d_in[5];  const float* b1 = (const float*)d_in[6];
    const float* W2 = (const float*)d_in[7];  const float* b2 = (const float*)d_in[8];
    const float* W3 = (const float*)d_in[9];  const float* b3 = (const float*)d_in[10];
    const float* W4 = (const float*)d_in[11]; const float* b4 = (const float*)d_in[12];
    const float* Wo1 = (const float*)d_in[13]; const float* bo1 = (const float*)d_in[14];
    const float* Wo2 = (const float*)d_in[15]; const float* bo2 = (const float*)d_in[16];
    float* out = (float*)d_out;

    const int N = in_sizes[2];
    const int E = in_sizes[1] / 2;
    const int G = out_size;
    const int* src = eidx;
    const int* dst = eidx + E;

    char* ws = (char*)d_ws;
    size_t off = 0;
    auto alloc = [&](size_t bytes) {
        size_t o = off;
        off += (bytes + 255) & ~(size_t)255;
        return o;
    };
    float* dis     = (float*)(ws + alloc((size_t)N * 4));
    int*   counts  = (int*)(ws + alloc((size_t)N * 4));
    int*   row_ptr = (int*)(ws + alloc((size_t)(N + 1) * 4));
    int*   cursor  = (int*)(ws + alloc((size_t)N * 4));
    int*   bsum    = (int*)(ws + alloc(64 * 4));
    uint2* edge_sw = (uint2*)(ws + alloc((size_t)E * 8));
    float* B1      = (float*)(ws + alloc((size_t)N * 96 * 4));
    float* B2      = (float*)(ws + alloc((size_t)N * 96 * 4));
    float* pmax    = (float*)(ws + alloc((size_t)G * 8 * 96 * 4));
    float* psum    = (float*)(ws + alloc((size_t)G * 8 * 96 * 4));
    float* pooled  = (float*)(ws + alloc((size_t)G * 192 * 4));
    (void)ws_size; (void)n_in;

    const int nbScan = (N + 2047) / 2048;
    const int nbTile = (N + 31) / 32;

    zero_i32<<<(N + 255) / 256, 256, 0, stream>>>(counts, N);
    count_kernel<<<(E + 255) / 256, 256, 0, stream>>>(dst, counts, E);
    scanA<<<nbScan, 256, 0, stream>>>(counts, row_ptr, bsum, dis, N);
    scanB<<<1, 64, 0, stream>>>(bsum, nbScan);
    scanC<<<(N + 255) / 256, 256, 0, stream>>>(row_ptr, cursor, bsum, N, E);
    fill_kernel<<<(E + 255) / 256, 256, 0, stream>>>(src, dst, cursor, dis, edge_sw, E);

    // Layer 0 (16 -> 96), fused agg+GEMM.
    layer_kernel<4, 1, 16><<<nbTile, 256, 0, stream>>>(x, dis, row_ptr, edge_sw,
                                                       W_init, b_init, B1, N);
    // Layers 1-4 (96 -> 96), fused, ping-pong B1/B2.
    const float* Ws[4] = {W1, W2, W3, W4};
    const float* bs[4] = {b1, b2, b3, b4};
    float* cur = B1;
    float* nxt = B2;
    for (int l = 0; l < 4; ++l) {
        layer_kernel<8, 3, 96><<<nbTile, 256, 0, stream>>>(cur, dis, row_ptr, edge_sw,
                                                           Ws[l], bs[l], nxt, N);
        float* t = cur; cur = nxt; nxt = t;
    }

    pool_partial<<<G * 8, 96, 0, stream>>>(cur, batch, pmax, psum, N);
    pool_reduce<<<G, 96, 0, stream>>>(pmax, psum, batch, pooled, N);
    mlp_kernel<<<G, 96, 0, stream>>>(pooled, Wo1, bo1, Wo2, bo2, out);
}

// Round 6
// 517.676 us; speedup vs baseline: 1.1905x; 1.1905x over previous
//
#include <hip/hip_runtime.h>
#include <math.h>

#define LEAKY(x) ((x) > 0.f ? (x) : 0.01f * (x))

__device__ __forceinline__ void fma4(float4& acc, float s, const float4& v) {
    acc.x += s * v.x; acc.y += s * v.y; acc.z += s * v.z; acc.w += s * v.w;
}

__global__ void zero_i32(int* p, int n) {
    int i = blockIdx.x * 256 + threadIdx.x;
    if (i < n) p[i] = 0;
}

__global__ void count_kernel(const int* __restrict__ dst, int* __restrict__ counts, int E) {
    int e = blockIdx.x * 256 + threadIdx.x;
    if (e < E) atomicAdd(&counts[dst[e]], 1);
}

// Stage A: per-block (2048 elems) local exclusive scan into row_ptr, block sums
// into bsum, and dis = rsqrt(count+1) folded in.
__global__ __launch_bounds__(256) void scanA(const int* __restrict__ counts,
                                             int* __restrict__ row_ptr,
                                             int* __restrict__ bsum,
                                             float* __restrict__ dis, int n) {
    __shared__ int sm[256];
    int base = blockIdx.x * 2048 + threadIdx.x * 8;
    int v[8];
    int s = 0;
#pragma unroll
    for (int j = 0; j < 8; ++j) {
        int i = base + j;
        int c = (i < n) ? counts[i] : 0;
        v[j] = c;
        s += c;
        if (i < n) dis[i] = rsqrtf((float)(c + 1));  // +1: self-loop
    }
    sm[threadIdx.x] = s;
    __syncthreads();
    for (int off = 1; off < 256; off <<= 1) {
        int t = (threadIdx.x >= off) ? sm[threadIdx.x - off] : 0;
        __syncthreads();
        sm[threadIdx.x] += t;
        __syncthreads();
    }
    int excl = sm[threadIdx.x] - s;
#pragma unroll
    for (int j = 0; j < 8; ++j) {
        int i = base + j;
        if (i < n) row_ptr[i] = excl;
        excl += v[j];
    }
    if (threadIdx.x == 255) bsum[blockIdx.x] = sm[255];
}

// Stage B: single-wave exclusive scan of block sums (nb <= 64).
__global__ __launch_bounds__(64) void scanB(int* __restrict__ bsum, int nb) {
    __shared__ int sm[64];
    int v = (threadIdx.x < nb) ? bsum[threadIdx.x] : 0;
    sm[threadIdx.x] = v;
    __syncthreads();
    for (int off = 1; off < 64; off <<= 1) {
        int t = (threadIdx.x >= off) ? sm[threadIdx.x - off] : 0;
        __syncthreads();
        sm[threadIdx.x] += t;
        __syncthreads();
    }
    if (threadIdx.x < nb) bsum[threadIdx.x] = sm[threadIdx.x] - v;
}

// Stage C: add block offsets, copy to cursor, write row_ptr[n] = E.
__global__ void scanC(int* __restrict__ row_ptr, int* __restrict__ cursor,
                      const int* __restrict__ bsum, int n, int E) {
    int i = blockIdx.x * 256 + threadIdx.x;
    if (i < n) {
        int v = row_ptr[i] + bsum[i >> 11];
        row_ptr[i] = v;
        cursor[i] = v;
    }
    if (i == 0) row_ptr[n] = E;
}

// CSR fill; stores (src, dis[src]) packed so agg does a single 8B load per edge.
__global__ void fill_kernel(const int* __restrict__ src, const int* __restrict__ dst,
                            int* __restrict__ cursor, const float* __restrict__ dis,
                            uint2* __restrict__ edge_sw, int E) {
    int e = blockIdx.x * 256 + threadIdx.x;
    if (e < E) {
        int s = src[e];
        int pos = atomicAdd(&cursor[dst[e]], 1);
        edge_sw[pos] = make_uint2((unsigned)s, __float_as_uint(dis[s]));
    }
}

// Wave-per-node edge-parallel aggregation:
//   A[i] = dis_i * ( sum_{s in in(i)} dis_s * X_s + dis_i * X_i )
// 64-lane wave = GROUPS edge-groups x LPN feature lanes (F4PL float4 each).
// Each round keeps GROUPS edges (GROUPS*K*4 bytes) in flight per wave; no LDS,
// no trailing barrier, loop bounds wave-uniform (one node per wave).
template <int LPN, int F4PL>
__global__ __launch_bounds__(256) void agg_wave(const float* __restrict__ X,
                                                const float* __restrict__ dis,
                                                const int* __restrict__ row_ptr,
                                                const uint2* __restrict__ edge_sw,
                                                float* __restrict__ A, int n) {
    constexpr int GROUPS = 64 / LPN;
    constexpr int KQ = LPN * F4PL;  // float4 per node row
    int i = (blockIdx.x * 256 + threadIdx.x) >> 6;  // node = global wave id
    if (i >= n) return;
    int lane = threadIdx.x & 63;
    int g = lane / LPN;   // edge group
    int c = lane % LPN;   // feature lane
    const float4* X4 = (const float4*)X;
    float di = dis[i];
    size_t base = (size_t)i * KQ + c * F4PL;
    float4 acc[F4PL];
    if (g == 0) {  // self-loop term di * X_i
#pragma unroll
        for (int j = 0; j < F4PL; ++j) {
            float4 xv = X4[base + j];
            acc[j] = make_float4(di * xv.x, di * xv.y, di * xv.z, di * xv.w);
        }
    } else {
#pragma unroll
        for (int j = 0; j < F4PL; ++j) acc[j] = make_float4(0.f, 0.f, 0.f, 0.f);
    }
    int re0 = row_ptr[i], re1 = row_ptr[i + 1];
    for (int e = re0 + g; e < re1; e += GROUPS) {
        uint2 ew = edge_sw[e];
        float ds = __uint_as_float(ew.y);
        size_t sb = (size_t)(int)ew.x * KQ + c * F4PL;
#pragma unroll
        for (int j = 0; j < F4PL; ++j) {
            float4 xs = X4[sb + j];
            fma4(acc[j], ds, xs);
        }
    }
    // Butterfly reduce across edge groups (lanes with equal c).
#pragma unroll
    for (int m = LPN; m < 64; m <<= 1) {
#pragma unroll
        for (int j = 0; j < F4PL; ++j) {
            acc[j].x += __shfl_xor(acc[j].x, m);
            acc[j].y += __shfl_xor(acc[j].y, m);
            acc[j].z += __shfl_xor(acc[j].z, m);
            acc[j].w += __shfl_xor(acc[j].w, m);
        }
    }
    if (g == 0) {
#pragma unroll
        for (int j = 0; j < F4PL; ++j) {
            float4 o = make_float4(di * acc[j].x, di * acc[j].y,
                                   di * acc[j].z, di * acc[j].w);
            ((float4*)A)[base + j] = o;
        }
    }
}

// Xn[i,f] = leaky( sum_k A[i,k]*W[k,f] + b[f] ),  W row-major [K,96], out width 96.
// 192 threads = 24 f-quads x 8 row-groups; 64 nodes/block, 8 rows x 4 f each.
// A-tile in LDS (24.6 KB); W read from global (wave-broadcast, L1/L2-resident).
template <int K>
__global__ __launch_bounds__(192) void gemm_act_kernel(const float* __restrict__ A,
                                                       const float* __restrict__ W,
                                                       const float* __restrict__ b,
                                                       float* __restrict__ Xn, int n) {
    constexpr int KQ = K / 4;
    __shared__ __align__(16) float4 Al[64 * KQ];
    int tid = threadIdx.x;
    int i0 = blockIdx.x * 64;
    for (int idx = tid; idx < 64 * KQ; idx += 192) {
        int gi = i0 + idx / KQ;
        Al[idx] = (gi < n) ? ((const float4*)A)[(size_t)i0 * KQ + idx]
                           : make_float4(0.f, 0.f, 0.f, 0.f);
    }
    __syncthreads();
    int fq = tid % 24;  // output float4 column
    int g = tid / 24;   // row group: rows g*8 .. g*8+7
    const float4* W4 = (const float4*)W;  // W4[k*24 + fq]
    float4 bb = ((const float4*)b)[fq];
    float4 acc[8];
#pragma unroll
    for (int r = 0; r < 8; ++r) acc[r] = bb;
    for (int kc = 0; kc < K; kc += 8) {
        float4 w[8];
#pragma unroll
        for (int kk = 0; kk < 8; ++kk) w[kk] = W4[(size_t)(kc + kk) * 24 + fq];
#pragma unroll
        for (int r = 0; r < 8; ++r) {
            const float4* ar = &Al[(g * 8 + r) * KQ + (kc >> 2)];
#pragma unroll
            for (int k4 = 0; k4 < 2; ++k4) {
                float4 a = ar[k4];
                float4 w0 = w[4 * k4 + 0], w1 = w[4 * k4 + 1];
                float4 w2 = w[4 * k4 + 2], w3 = w[4 * k4 + 3];
                acc[r].x += a.x * w0.x + a.y * w1.x + a.z * w2.x + a.w * w3.x;
                acc[r].y += a.x * w0.y + a.y * w1.y + a.z * w2.y + a.w * w3.y;
                acc[r].z += a.x * w0.z + a.y * w1.z + a.z * w2.z + a.w * w3.z;
                acc[r].w += a.x * w0.w + a.y * w1.w + a.z * w2.w + a.w * w3.w;
            }
        }
    }
#pragma unroll
    for (int r = 0; r < 8; ++r) {
        int gi = i0 + g * 8 + r;
        if (gi < n) {
            float4 o;
            o.x = LEAKY(acc[r].x); o.y = LEAKY(acc[r].y);
            o.z = LEAKY(acc[r].z); o.w = LEAKY(acc[r].w);
            ((float4*)Xn)[(size_t)gi * 24 + fq] = o;
        }
    }
}

__device__ __forceinline__ int lower_bound(const int* b, int n, int v) {
    int lo = 0, hi = n;
    while (lo < hi) {
        int m = (lo + hi) >> 1;
        if (b[m] < v) lo = m + 1; else hi = m;
    }
    return lo;
}

// grid = G*8, block = 96. Chunked per-graph partial max/sum.
__global__ void pool_partial(const float* __restrict__ X, const int* __restrict__ batch,
                             float* __restrict__ pmax, float* __restrict__ psum, int n) {
    int g = blockIdx.x / 8, ch = blockIdx.x % 8;
    int f = threadIdx.x;
    int s = lower_bound(batch, n, g), e = lower_bound(batch, n, g + 1);
    int len = e - s;
    int cs = s + (int)((long)len * ch / 8);
    int ce = s + (int)((long)len * (ch + 1) / 8);
    float mx = -INFINITY, sm = 0.f;
    for (int i = cs; i < ce; ++i) {
        float v = X[(size_t)i * 96 + f];
        mx = fmaxf(mx, v);
        sm += v;
    }
    pmax[(size_t)blockIdx.x * 96 + f] = mx;
    psum[(size_t)blockIdx.x * 96 + f] = sm;
}

__global__ void pool_reduce(const float* __restrict__ pmax, const float* __restrict__ psum,
                            const int* __restrict__ batch, float* __restrict__ pooled, int n) {
    int g = blockIdx.x, f = threadIdx.x;
    float mx = -INFINITY, sm = 0.f;
    for (int c = 0; c < 8; ++c) {
        mx = fmaxf(mx, pmax[(size_t)(g * 8 + c) * 96 + f]);
        sm += psum[(size_t)(g * 8 + c) * 96 + f];
    }
    int s = lower_bound(batch, n, g), e = lower_bound(batch, n, g + 1);
    float cnt = fmaxf((float)(e - s), 1.f);
    pooled[g * 192 + f] = mx;
    pooled[g * 192 + 96 + f] = sm / cnt;
}

// out[g] = leaky(pooled[g]@Wo1 + bo1) @ Wo2 + bo2
__global__ void mlp_kernel(const float* __restrict__ pooled, const float* __restrict__ Wo1,
                           const float* __restrict__ bo1, const float* __restrict__ Wo2,
                           const float* __restrict__ bo2, float* __restrict__ out) {
    __shared__ float sh[96];
    int g = blockIdx.x, f = threadIdx.x;
    float acc = bo1[f];
    for (int k = 0; k < 192; ++k) acc += pooled[g * 192 + k] * Wo1[k * 96 + f];
    float a = LEAKY(acc);
    sh[f] = a * Wo2[f];
    __syncthreads();
    if (f == 0) {
        float sacc = 0.f;
        for (int k = 0; k < 96; ++k) sacc += sh[k];
        out[g] = sacc + bo2[0];
    }
}

extern "C" void kernel_launch(void* const* d_in, const int* in_sizes, int n_in,
                              void* d_out, int out_size, void* d_ws, size_t ws_size,
                              hipStream_t stream) {
    const float* x      = (const float*)d_in[0];
    const int*   eidx   = (const int*)d_in[1];
    const int*   batch  = (const int*)d_in[2];
    const float* W_init = (const float*)d_in[3];
    const float* b_init = (const float*)d_in[4];
    const float* W1 = (const float*)d_in[5];  const float* b1 = (const float*)d_in[6];
    const float* W2 = (const float*)d_in[7];  const float* b2 = (const float*)d_in[8];
    const float* W3 = (const float*)d_in[9];  const float* b3 = (const float*)d_in[10];
    const float* W4 = (const float*)d_in[11]; const float* b4 = (const float*)d_in[12];
    const float* Wo1 = (const float*)d_in[13]; const float* bo1 = (const float*)d_in[14];
    const float* Wo2 = (const float*)d_in[15]; const float* bo2 = (const float*)d_in[16];
    float* out = (float*)d_out;

    const int N = in_sizes[2];
    const int E = in_sizes[1] / 2;
    const int G = out_size;
    const int* src = eidx;
    const int* dst = eidx + E;

    char* ws = (char*)d_ws;
    size_t off = 0;
    auto alloc = [&](size_t bytes) {
        size_t o = off;
        off += (bytes + 255) & ~(size_t)255;
        return o;
    };
    float* dis     = (float*)(ws + alloc((size_t)N * 4));
    int*   counts  = (int*)(ws + alloc((size_t)N * 4));
    int*   row_ptr = (int*)(ws + alloc((size_t)(N + 1) * 4));
    int*   cursor  = (int*)(ws + alloc((size_t)N * 4));
    int*   bsum    = (int*)(ws + alloc(64 * 4));
    uint2* edge_sw = (uint2*)(ws + alloc((size_t)E * 8));
    float* B1      = (float*)(ws + alloc((size_t)N * 96 * 4));
    float* B2      = (float*)(ws + alloc((size_t)N * 96 * 4));
    float* pmax    = (float*)(ws + alloc((size_t)G * 8 * 96 * 4));
    float* psum    = (float*)(ws + alloc((size_t)G * 8 * 96 * 4));
    float* pooled  = (float*)(ws + alloc((size_t)G * 192 * 4));
    (void)ws_size; (void)n_in;

    const int nbScan = (N + 2047) / 2048;
    const int nbWave = (N + 3) / 4;       // 4 nodes (waves) per 256-thread block
    const int nbTile = (N + 63) / 64;

    zero_i32<<<(N + 255) / 256, 256, 0, stream>>>(counts, N);
    count_kernel<<<(E + 255) / 256, 256, 0, stream>>>(dst, counts, E);
    scanA<<<nbScan, 256, 0, stream>>>(counts, row_ptr, bsum, dis, N);
    scanB<<<1, 64, 0, stream>>>(bsum, nbScan);
    scanC<<<(N + 255) / 256, 256, 0, stream>>>(row_ptr, cursor, bsum, N, E);
    fill_kernel<<<(E + 255) / 256, 256, 0, stream>>>(src, dst, cursor, dis, edge_sw, E);

    // Layer 0: aggregate 16-wide input (16 edge-groups x 4 lanes), then 16x96 GEMM.
    agg_wave<4, 1><<<nbWave, 256, 0, stream>>>(x, dis, row_ptr, edge_sw, B2, N);
    gemm_act_kernel<16><<<nbTile, 192, 0, stream>>>(B2, W_init, b_init, B1, N);

    const float* Ws[4] = {W1, W2, W3, W4};
    const float* bs[4] = {b1, b2, b3, b4};
    for (int l = 0; l < 4; ++l) {
        agg_wave<8, 3><<<nbWave, 256, 0, stream>>>(B1, dis, row_ptr, edge_sw, B2, N);
        gemm_act_kernel<96><<<nbTile, 192, 0, stream>>>(B2, Ws[l], bs[l], B1, N);
    }

    pool_partial<<<G * 8, 96, 0, stream>>>(B1, batch, pmax, psum, N);
    pool_reduce<<<G, 96, 0, stream>>>(pmax, psum, batch, pooled, N);
    mlp_kernel<<<G, 96, 0, stream>>>(pooled, Wo1, bo1, Wo2, bo2, out);
}

// Round 7
// 516.594 us; speedup vs baseline: 1.1930x; 1.0021x over previous
//
#include <hip/hip_runtime.h>
#include <math.h>

#define LEAKY(x) ((x) > 0.f ? (x) : 0.01f * (x))

__device__ __forceinline__ void add4(float4& acc, const float4& v) {
    acc.x += v.x; acc.y += v.y; acc.z += v.z; acc.w += v.w;
}

__global__ void zero_i32(int* p, int n) {
    int i = blockIdx.x * 256 + threadIdx.x;
    if (i < n) p[i] = 0;
}

__global__ void count_kernel(const int* __restrict__ dst, int* __restrict__ counts, int E) {
    int e = blockIdx.x * 256 + threadIdx.x;
    if (e < E) atomicAdd(&counts[dst[e]], 1);
}

// Stage A: per-block (2048 elems) local exclusive scan into row_ptr, block sums
// into bsum, and dis = rsqrt(count+1) folded in.
__global__ __launch_bounds__(256) void scanA(const int* __restrict__ counts,
                                             int* __restrict__ row_ptr,
                                             int* __restrict__ bsum,
                                             float* __restrict__ dis, int n) {
    __shared__ int sm[256];
    int base = blockIdx.x * 2048 + threadIdx.x * 8;
    int v[8];
    int s = 0;
#pragma unroll
    for (int j = 0; j < 8; ++j) {
        int i = base + j;
        int c = (i < n) ? counts[i] : 0;
        v[j] = c;
        s += c;
        if (i < n) dis[i] = rsqrtf((float)(c + 1));  // +1: self-loop
    }
    sm[threadIdx.x] = s;
    __syncthreads();
    for (int off = 1; off < 256; off <<= 1) {
        int t = (threadIdx.x >= off) ? sm[threadIdx.x - off] : 0;
        __syncthreads();
        sm[threadIdx.x] += t;
        __syncthreads();
    }
    int excl = sm[threadIdx.x] - s;
#pragma unroll
    for (int j = 0; j < 8; ++j) {
        int i = base + j;
        if (i < n) row_ptr[i] = excl;
        excl += v[j];
    }
    if (threadIdx.x == 255) bsum[blockIdx.x] = sm[255];
}

// Stage B: single-wave exclusive scan of block sums (nb <= 64).
__global__ __launch_bounds__(64) void scanB(int* __restrict__ bsum, int nb) {
    __shared__ int sm[64];
    int v = (threadIdx.x < nb) ? bsum[threadIdx.x] : 0;
    sm[threadIdx.x] = v;
    __syncthreads();
    for (int off = 1; off < 64; off <<= 1) {
        int t = (threadIdx.x >= off) ? sm[threadIdx.x - off] : 0;
        __syncthreads();
        sm[threadIdx.x] += t;
        __syncthreads();
    }
    if (threadIdx.x < nb) bsum[threadIdx.x] = sm[threadIdx.x] - v;
}

// Stage C: add block offsets, copy to cursor, write row_ptr[n] = E.
__global__ void scanC(int* __restrict__ row_ptr, int* __restrict__ cursor,
                      const int* __restrict__ bsum, int n, int E) {
    int i = blockIdx.x * 256 + threadIdx.x;
    if (i < n) {
        int v = row_ptr[i] + bsum[i >> 11];
        row_ptr[i] = v;
        cursor[i] = v;
    }
    if (i == 0) row_ptr[n] = E;
}

// CSR fill; 4-byte payload (src only) — dis is folded into Z = dis*X, halving
// the cross-XCD scattered write traffic vs the old (src,weight) uint2.
__global__ void fill_kernel(const int* __restrict__ src, const int* __restrict__ dst,
                            int* __restrict__ cursor, int* __restrict__ edge_src, int E) {
    int e = blockIdx.x * 256 + threadIdx.x;
    if (e < E) {
        int s = src[e];
        int pos = atomicAdd(&cursor[dst[e]], 1);
        edge_src[pos] = s;
    }
}

// Z0 = dis * x  (layer-0 input pre-scale), one float4 per thread.
__global__ void scale_kernel(const float* __restrict__ X, const float* __restrict__ dis,
                             float* __restrict__ Z, int n4, int kq) {
    int id = blockIdx.x * 256 + threadIdx.x;
    if (id < n4) {
        float di = dis[id / kq];
        float4 v = ((const float4*)X)[id];
        ((float4*)Z)[id] = make_float4(di * v.x, di * v.y, di * v.z, di * v.w);
    }
}

// Wave-per-node edge-parallel aggregation over pre-scaled features Z:
//   A[i] = dis_i * ( sum_{s in in(i)} Z_s + Z_i )
// 64-lane wave = GROUPS edge-groups x LPN feature lanes (F4PL float4 each).
// Pure-add inner loop (no per-edge weight), no LDS, no barrier.
template <int LPN, int F4PL>
__global__ __launch_bounds__(256) void agg_wave(const float* __restrict__ Z,
                                                const float* __restrict__ dis,
                                                const int* __restrict__ row_ptr,
                                                const int* __restrict__ edge_src,
                                                float* __restrict__ A, int n) {
    constexpr int GROUPS = 64 / LPN;
    constexpr int KQ = LPN * F4PL;  // float4 per node row
    int i = (blockIdx.x * 256 + threadIdx.x) >> 6;  // node = global wave id
    if (i >= n) return;
    int lane = threadIdx.x & 63;
    int g = lane / LPN;   // edge group
    int c = lane % LPN;   // feature lane
    const float4* Z4 = (const float4*)Z;
    float di = dis[i];
    size_t base = (size_t)i * KQ + c * F4PL;
    float4 acc[F4PL];
    if (g == 0) {  // self-loop term Z_i
#pragma unroll
        for (int j = 0; j < F4PL; ++j) acc[j] = Z4[base + j];
    } else {
#pragma unroll
        for (int j = 0; j < F4PL; ++j) acc[j] = make_float4(0.f, 0.f, 0.f, 0.f);
    }
    int re0 = row_ptr[i], re1 = row_ptr[i + 1];
#pragma unroll 2
    for (int e = re0 + g; e < re1; e += GROUPS) {
        int s = edge_src[e];
        size_t sb = (size_t)s * KQ + c * F4PL;
#pragma unroll
        for (int j = 0; j < F4PL; ++j) {
            float4 xs = Z4[sb + j];
            add4(acc[j], xs);
        }
    }
    // Butterfly reduce across edge groups (lanes with equal c).
#pragma unroll
    for (int m = LPN; m < 64; m <<= 1) {
#pragma unroll
        for (int j = 0; j < F4PL; ++j) {
            acc[j].x += __shfl_xor(acc[j].x, m);
            acc[j].y += __shfl_xor(acc[j].y, m);
            acc[j].z += __shfl_xor(acc[j].z, m);
            acc[j].w += __shfl_xor(acc[j].w, m);
        }
    }
    if (g == 0) {
#pragma unroll
        for (int j = 0; j < F4PL; ++j) {
            float4 o = make_float4(di * acc[j].x, di * acc[j].y,
                                   di * acc[j].z, di * acc[j].w);
            ((float4*)A)[base + j] = o;
        }
    }
}

// Xn[i,f] = leaky( sum_k A[i,k]*W[k,f] + b[f] ), optionally * dis[i] (to produce
// the next layer's pre-scaled Z). W row-major [K,96], out width 96.
// 192 threads = 24 f-quads x 8 row-groups; 64 nodes/block, 8 rows x 4 f each.
// A-tile in LDS (24.6 KB); W read from global (wave-broadcast, L1/L2-resident).
template <int K, bool SCALE>
__global__ __launch_bounds__(192) void gemm_act_kernel(const float* __restrict__ A,
                                                       const float* __restrict__ W,
                                                       const float* __restrict__ b,
                                                       const float* __restrict__ dis,
                                                       float* __restrict__ Xn, int n) {
    constexpr int KQ = K / 4;
    __shared__ __align__(16) float4 Al[64 * KQ];
    int tid = threadIdx.x;
    int i0 = blockIdx.x * 64;
    for (int idx = tid; idx < 64 * KQ; idx += 192) {
        int gi = i0 + idx / KQ;
        Al[idx] = (gi < n) ? ((const float4*)A)[(size_t)i0 * KQ + idx]
                           : make_float4(0.f, 0.f, 0.f, 0.f);
    }
    __syncthreads();
    int fq = tid % 24;  // output float4 column
    int g = tid / 24;   // row group: rows g*8 .. g*8+7
    const float4* W4 = (const float4*)W;  // W4[k*24 + fq]
    float4 bb = ((const float4*)b)[fq];
    float4 acc[8];
#pragma unroll
    for (int r = 0; r < 8; ++r) acc[r] = bb;
    for (int kc = 0; kc < K; kc += 8) {
        float4 w[8];
#pragma unroll
        for (int kk = 0; kk < 8; ++kk) w[kk] = W4[(size_t)(kc + kk) * 24 + fq];
#pragma unroll
        for (int r = 0; r < 8; ++r) {
            const float4* ar = &Al[(g * 8 + r) * KQ + (kc >> 2)];
#pragma unroll
            for (int k4 = 0; k4 < 2; ++k4) {
                float4 a = ar[k4];
                float4 w0 = w[4 * k4 + 0], w1 = w[4 * k4 + 1];
                float4 w2 = w[4 * k4 + 2], w3 = w[4 * k4 + 3];
                acc[r].x += a.x * w0.x + a.y * w1.x + a.z * w2.x + a.w * w3.x;
                acc[r].y += a.x * w0.y + a.y * w1.y + a.z * w2.y + a.w * w3.y;
                acc[r].z += a.x * w0.z + a.y * w1.z + a.z * w2.z + a.w * w3.z;
                acc[r].w += a.x * w0.w + a.y * w1.w + a.z * w2.w + a.w * w3.w;
            }
        }
    }
#pragma unroll
    for (int r = 0; r < 8; ++r) {
        int gi = i0 + g * 8 + r;
        if (gi < n) {
            float4 o;
            o.x = LEAKY(acc[r].x); o.y = LEAKY(acc[r].y);
            o.z = LEAKY(acc[r].z); o.w = LEAKY(acc[r].w);
            if (SCALE) {
                float di = dis[gi];
                o.x *= di; o.y *= di; o.z *= di; o.w *= di;
            }
            ((float4*)Xn)[(size_t)gi * 24 + fq] = o;
        }
    }
}

__device__ __forceinline__ int lower_bound(const int* b, int n, int v) {
    int lo = 0, hi = n;
    while (lo < hi) {
        int m = (lo + hi) >> 1;
        if (b[m] < v) lo = m + 1; else hi = m;
    }
    return lo;
}

// grid = G*8, block = 96. Chunked per-graph partial max/sum.
__global__ void pool_partial(const float* __restrict__ X, const int* __restrict__ batch,
                             float* __restrict__ pmax, float* __restrict__ psum, int n) {
    int g = blockIdx.x / 8, ch = blockIdx.x % 8;
    int f = threadIdx.x;
    int s = lower_bound(batch, n, g), e = lower_bound(batch, n, g + 1);
    int len = e - s;
    int cs = s + (int)((long)len * ch / 8);
    int ce = s + (int)((long)len * (ch + 1) / 8);
    float mx = -INFINITY, sm = 0.f;
    for (int i = cs; i < ce; ++i) {
        float v = X[(size_t)i * 96 + f];
        mx = fmaxf(mx, v);
        sm += v;
    }
    pmax[(size_t)blockIdx.x * 96 + f] = mx;
    psum[(size_t)blockIdx.x * 96 + f] = sm;
}

__global__ void pool_reduce(const float* __restrict__ pmax, const float* __restrict__ psum,
                            const int* __restrict__ batch, float* __restrict__ pooled, int n) {
    int g = blockIdx.x, f = threadIdx.x;
    float mx = -INFINITY, sm = 0.f;
    for (int c = 0; c < 8; ++c) {
        mx = fmaxf(mx, pmax[(size_t)(g * 8 + c) * 96 + f]);
        sm += psum[(size_t)(g * 8 + c) * 96 + f];
    }
    int s = lower_bound(batch, n, g), e = lower_bound(batch, n, g + 1);
    float cnt = fmaxf((float)(e - s), 1.f);
    pooled[g * 192 + f] = mx;
    pooled[g * 192 + 96 + f] = sm / cnt;
}

// out[g] = leaky(pooled[g]@Wo1 + bo1) @ Wo2 + bo2
__global__ void mlp_kernel(const float* __restrict__ pooled, const float* __restrict__ Wo1,
                           const float* __restrict__ bo1, const float* __restrict__ Wo2,
                           const float* __restrict__ bo2, float* __restrict__ out) {
    __shared__ float sh[96];
    int g = blockIdx.x, f = threadIdx.x;
    float acc = bo1[f];
    for (int k = 0; k < 192; ++k) acc += pooled[g * 192 + k] * Wo1[k * 96 + f];
    float a = LEAKY(acc);
    sh[f] = a * Wo2[f];
    __syncthreads();
    if (f == 0) {
        float sacc = 0.f;
        for (int k = 0; k < 96; ++k) sacc += sh[k];
        out[g] = sacc + bo2[0];
    }
}

extern "C" void kernel_launch(void* const* d_in, const int* in_sizes, int n_in,
                              void* d_out, int out_size, void* d_ws, size_t ws_size,
                              hipStream_t stream) {
    const float* x      = (const float*)d_in[0];
    const int*   eidx   = (const int*)d_in[1];
    const int*   batch  = (const int*)d_in[2];
    const float* W_init = (const float*)d_in[3];
    const float* b_init = (const float*)d_in[4];
    const float* W1 = (const float*)d_in[5];  const float* b1 = (const float*)d_in[6];
    const float* W2 = (const float*)d_in[7];  const float* b2 = (const float*)d_in[8];
    const float* W3 = (const float*)d_in[9];  const float* b3 = (const float*)d_in[10];
    const float* W4 = (const float*)d_in[11]; const float* b4 = (const float*)d_in[12];
    const float* Wo1 = (const float*)d_in[13]; const float* bo1 = (const float*)d_in[14];
    const float* Wo2 = (const float*)d_in[15]; const float* bo2 = (const float*)d_in[16];
    float* out = (float*)d_out;

    const int N = in_sizes[2];
    const int E = in_sizes[1] / 2;
    const int G = out_size;
    const int* src = eidx;
    const int* dst = eidx + E;

    char* ws = (char*)d_ws;
    size_t off = 0;
    auto alloc = [&](size_t bytes) {
        size_t o = off;
        off += (bytes + 255) & ~(size_t)255;
        return o;
    };
    float* dis     = (float*)(ws + alloc((size_t)N * 4));
    int*   counts  = (int*)(ws + alloc((size_t)N * 4));
    int*   row_ptr = (int*)(ws + alloc((size_t)(N + 1) * 4));
    int*   cursor  = (int*)(ws + alloc((size_t)N * 4));
    int*   bsum    = (int*)(ws + alloc(64 * 4));
    int*   edge_src= (int*)(ws + alloc((size_t)E * 4));
    float* Z0      = (float*)(ws + alloc((size_t)N * 16 * 4));
    float* ZA      = (float*)(ws + alloc((size_t)N * 96 * 4));
    float* ZB      = (float*)(ws + alloc((size_t)N * 96 * 4));
    float* Agg     = (float*)(ws + alloc((size_t)N * 96 * 4));
    float* pmax    = (float*)(ws + alloc((size_t)G * 8 * 96 * 4));
    float* psum    = (float*)(ws + alloc((size_t)G * 8 * 96 * 4));
    float* pooled  = (float*)(ws + alloc((size_t)G * 192 * 4));
    (void)ws_size; (void)n_in;

    const int nbScan = (N + 2047) / 2048;
    const int nbWave = (N + 3) / 4;       // 4 nodes (waves) per 256-thread block
    const int nbTile = (N + 63) / 64;

    zero_i32<<<(N + 255) / 256, 256, 0, stream>>>(counts, N);
    count_kernel<<<(E + 255) / 256, 256, 0, stream>>>(dst, counts, E);
    scanA<<<nbScan, 256, 0, stream>>>(counts, row_ptr, bsum, dis, N);
    scanB<<<1, 64, 0, stream>>>(bsum, nbScan);
    scanC<<<(N + 255) / 256, 256, 0, stream>>>(row_ptr, cursor, bsum, N, E);
    fill_kernel<<<(E + 255) / 256, 256, 0, stream>>>(src, dst, cursor, edge_src, E);
    scale_kernel<<<(N * 4 + 255) / 256, 256, 0, stream>>>(x, dis, Z0, N * 4, 4);

    // Layer 0: aggregate pre-scaled 16-wide input, then 16x96 GEMM (-> Z1).
    agg_wave<4, 1><<<nbWave, 256, 0, stream>>>(Z0, dis, row_ptr, edge_src, Agg, N);
    gemm_act_kernel<16, true><<<nbTile, 192, 0, stream>>>(Agg, W_init, b_init, dis, ZA, N);

    const float* Ws[4] = {W1, W2, W3, W4};
    const float* bs[4] = {b1, b2, b3, b4};
    float* cur = ZA;
    float* nxt = ZB;
    for (int l = 0; l < 4; ++l) {
        agg_wave<8, 3><<<nbWave, 256, 0, stream>>>(cur, dis, row_ptr, edge_src, Agg, N);
        if (l < 3)
            gemm_act_kernel<96, true><<<nbTile, 192, 0, stream>>>(Agg, Ws[l], bs[l], dis, nxt, N);
        else  // last layer: pooling needs the unscaled activation H
            gemm_act_kernel<96, false><<<nbTile, 192, 0, stream>>>(Agg, Ws[l], bs[l], dis, nxt, N);
        float* t = cur; cur = nxt; nxt = t;
    }

    pool_partial<<<G * 8, 96, 0, stream>>>(cur, batch, pmax, psum, N);
    pool_reduce<<<G, 96, 0, stream>>>(pmax, psum, batch, pooled, N);
    mlp_kernel<<<G, 96, 0, stream>>>(pooled, Wo1, bo1, Wo2, bo2, out);
}

// Round 8
// 511.173 us; speedup vs baseline: 1.2057x; 1.0106x over previous
//
#include <hip/hip_runtime.h>
#include <math.h>

#define LEAKY(x) ((x) > 0.f ? (x) : 0.01f * (x))
#define BK_SHIFT 9            // 512 nodes per bucket
#define NBMAX 128             // supports N <= 65536

__device__ __forceinline__ void add4(float4& acc, const float4& v) {
    acc.x += v.x; acc.y += v.y; acc.z += v.z; acc.w += v.w;
}

__global__ void zero_i32(int* p, int n) {
    int i = blockIdx.x * 256 + threadIdx.x;
    if (i < n) p[i] = 0;
}

__global__ void count_kernel(const int* __restrict__ dst, int* __restrict__ counts, int E) {
    int e = blockIdx.x * 256 + threadIdx.x;
    if (e < E) atomicAdd(&counts[dst[e]], 1);
}

// Stage A: per-block (2048 elems) local exclusive scan into row_ptr, block sums
// into bsum, and dis = rsqrt(count+1) folded in.
__global__ __launch_bounds__(256) void scanA(const int* __restrict__ counts,
                                             int* __restrict__ row_ptr,
                                             int* __restrict__ bsum,
                                             float* __restrict__ dis, int n) {
    __shared__ int sm[256];
    int base = blockIdx.x * 2048 + threadIdx.x * 8;
    int v[8];
    int s = 0;
#pragma unroll
    for (int j = 0; j < 8; ++j) {
        int i = base + j;
        int c = (i < n) ? counts[i] : 0;
        v[j] = c;
        s += c;
        if (i < n) dis[i] = rsqrtf((float)(c + 1));  // +1: self-loop
    }
    sm[threadIdx.x] = s;
    __syncthreads();
    for (int off = 1; off < 256; off <<= 1) {
        int t = (threadIdx.x >= off) ? sm[threadIdx.x - off] : 0;
        __syncthreads();
        sm[threadIdx.x] += t;
        __syncthreads();
    }
    int excl = sm[threadIdx.x] - s;
#pragma unroll
    for (int j = 0; j < 8; ++j) {
        int i = base + j;
        if (i < n) row_ptr[i] = excl;
        excl += v[j];
    }
    if (threadIdx.x == 255) bsum[blockIdx.x] = sm[255];
}

// Stage B: single-wave exclusive scan of block sums (nb <= 64).
__global__ __launch_bounds__(64) void scanB(int* __restrict__ bsum, int nb) {
    __shared__ int sm[64];
    int v = (threadIdx.x < nb) ? bsum[threadIdx.x] : 0;
    sm[threadIdx.x] = v;
    __syncthreads();
    for (int off = 1; off < 64; off <<= 1) {
        int t = (threadIdx.x >= off) ? sm[threadIdx.x - off] : 0;
        __syncthreads();
        sm[threadIdx.x] += t;
        __syncthreads();
    }
    if (threadIdx.x < nb) bsum[threadIdx.x] = sm[threadIdx.x] - v;
}

// Stage C: add block offsets, copy to cursor, init per-bucket cursors,
// write row_ptr[n] = E.
__global__ void scanC(int* __restrict__ row_ptr, int* __restrict__ cursor,
                      int* __restrict__ bkt_cursor, const int* __restrict__ bsum,
                      int n, int E) {
    int i = blockIdx.x * 256 + threadIdx.x;
    if (i < n) {
        int v = row_ptr[i] + bsum[i >> 11];
        row_ptr[i] = v;
        cursor[i] = v;
        if ((i & ((1 << BK_SHIFT) - 1)) == 0) bkt_cursor[i >> BK_SHIFT] = v;
    }
    if (i == 0) row_ptr[n] = E;
}

// Pass 1 of CSR fill: LDS counting-sort 2048-edge chunks by 512-node bucket,
// reserve per-bucket spans, flush contiguous runs to tmp (bucket-major layout
// identical to the final CSR bucket slices). Converts the random 4B scatter
// into ~full-line coalesced runs.
__global__ __launch_bounds__(256) void bin_kernel(const int* __restrict__ src,
                                                  const int* __restrict__ dst,
                                                  int* __restrict__ bkt_cursor,
                                                  uint2* __restrict__ tmp,
                                                  int E, int nb) {
    __shared__ int hist[NBMAX];
    __shared__ int scanbuf[NBMAX];
    __shared__ int lofs[NBMAX];
    __shared__ int adj[NBMAX];
    __shared__ uint2 buf[2048];
    __shared__ unsigned char bkt_of[2048];
    int base = blockIdx.x * 2048;
    int cnt = min(2048, E - base);
    int tid = threadIdx.x;
    for (int b = tid; b < NBMAX; b += 256) hist[b] = 0;
    __syncthreads();
    int es[8], ed[8];
#pragma unroll
    for (int k = 0; k < 8; ++k) {
        int l = tid + k * 256;
        if (l < cnt) {
            es[k] = src[base + l];
            ed[k] = dst[base + l];
            atomicAdd(&hist[ed[k] >> BK_SHIFT], 1);
        }
    }
    __syncthreads();
    // inclusive Hillis-Steele scan over NBMAX entries (threads 0..127)
    if (tid < NBMAX) scanbuf[tid] = hist[tid];
    __syncthreads();
    for (int off = 1; off < NBMAX; off <<= 1) {
        int t = (tid < NBMAX && tid >= off) ? scanbuf[tid - off] : 0;
        __syncthreads();
        if (tid < NBMAX) scanbuf[tid] += t;
        __syncthreads();
    }
    if (tid < nb) {
        int cb = hist[tid];
        int start = scanbuf[tid] - cb;   // exclusive
        lofs[tid] = start;
        int g = (cb > 0) ? atomicAdd(&bkt_cursor[tid], cb) : 0;
        adj[tid] = g - start;
    }
    __syncthreads();
#pragma unroll
    for (int k = 0; k < 8; ++k) {
        int l = tid + k * 256;
        if (l < cnt) {
            int b = ed[k] >> BK_SHIFT;
            int r = atomicAdd(&lofs[b], 1);
            buf[r] = make_uint2((unsigned)es[k], (unsigned)ed[k]);
            bkt_of[r] = (unsigned char)b;
        }
    }
    __syncthreads();
    for (int j = tid; j < cnt; j += 256) {
        int b = bkt_of[j];
        tmp[adj[b] + j] = buf[j];
    }
}

// Pass 2: one block per bucket. Cursor window (2 KB) and CSR write window
// (~32 KB) are touched by exactly one CU -> one XCD L2 -> full-line writebacks.
__global__ __launch_bounds__(512) void place_kernel(const uint2* __restrict__ tmp,
                                                    const int* __restrict__ row_ptr,
                                                    int* __restrict__ cursor,
                                                    int* __restrict__ edge_src,
                                                    int n) {
    int b = blockIdx.x;
    int s = row_ptr[min(b << BK_SHIFT, n)];
    int e = row_ptr[min((b + 1) << BK_SHIFT, n)];
    for (int j = s + (int)threadIdx.x; j < e; j += 512) {
        uint2 ev = tmp[j];
        int pos = atomicAdd(&cursor[(int)ev.y], 1);
        edge_src[pos] = (int)ev.x;
    }
}

// Z0 = dis * x  (layer-0 input pre-scale), one float4 per thread.
__global__ void scale_kernel(const float* __restrict__ X, const float* __restrict__ dis,
                             float* __restrict__ Z, int n4, int kq) {
    int id = blockIdx.x * 256 + threadIdx.x;
    if (id < n4) {
        float di = dis[id / kq];
        float4 v = ((const float4*)X)[id];
        ((float4*)Z)[id] = make_float4(di * v.x, di * v.y, di * v.z, di * v.w);
    }
}

// Wave-per-node edge-parallel aggregation over pre-scaled features Z:
//   A[i] = dis_i * ( sum_{s in in(i)} Z_s + Z_i )
// 64-lane wave = GROUPS edge-groups x LPN feature lanes (F4PL float4 each).
template <int LPN, int F4PL, int UNROLL>
__global__ __launch_bounds__(256) void agg_wave(const float* __restrict__ Z,
                                                const float* __restrict__ dis,
                                                const int* __restrict__ row_ptr,
                                                const int* __restrict__ edge_src,
                                                float* __restrict__ A, int n) {
    constexpr int GROUPS = 64 / LPN;
    constexpr int KQ = LPN * F4PL;  // float4 per node row
    int i = (blockIdx.x * 256 + threadIdx.x) >> 6;  // node = global wave id
    if (i >= n) return;
    int lane = threadIdx.x & 63;
    int g = lane / LPN;   // edge group
    int c = lane % LPN;   // feature lane
    const float4* Z4 = (const float4*)Z;
    float di = dis[i];
    size_t base = (size_t)i * KQ + c * F4PL;
    float4 acc[F4PL];
    if (g == 0) {  // self-loop term Z_i
#pragma unroll
        for (int j = 0; j < F4PL; ++j) acc[j] = Z4[base + j];
    } else {
#pragma unroll
        for (int j = 0; j < F4PL; ++j) acc[j] = make_float4(0.f, 0.f, 0.f, 0.f);
    }
    int re0 = row_ptr[i], re1 = row_ptr[i + 1];
#pragma unroll UNROLL
    for (int e = re0 + g; e < re1; e += GROUPS) {
        int s = edge_src[e];
        size_t sb = (size_t)s * KQ + c * F4PL;
#pragma unroll
        for (int j = 0; j < F4PL; ++j) {
            float4 xs = Z4[sb + j];
            add4(acc[j], xs);
        }
    }
    // Butterfly reduce across edge groups (lanes with equal c).
#pragma unroll
    for (int m = LPN; m < 64; m <<= 1) {
#pragma unroll
        for (int j = 0; j < F4PL; ++j) {
            acc[j].x += __shfl_xor(acc[j].x, m);
            acc[j].y += __shfl_xor(acc[j].y, m);
            acc[j].z += __shfl_xor(acc[j].z, m);
            acc[j].w += __shfl_xor(acc[j].w, m);
        }
    }
    if (g == 0) {
#pragma unroll
        for (int j = 0; j < F4PL; ++j) {
            float4 o = make_float4(di * acc[j].x, di * acc[j].y,
                                   di * acc[j].z, di * acc[j].w);
            ((float4*)A)[base + j] = o;
        }
    }
}

// Xn[i,f] = leaky( sum_k A[i,k]*W[k,f] + b[f] ), optionally * dis[i] (to produce
// the next layer's pre-scaled Z). W row-major [K,96], out width 96.
// 192 threads = 24 f-quads x 8 row-groups; 64 nodes/block, 8 rows x 4 f each.
// A-tile in LDS (24.6 KB); W read from global (wave-broadcast, L1/L2-resident).
template <int K, bool SCALE>
__global__ __launch_bounds__(192) void gemm_act_kernel(const float* __restrict__ A,
                                                       const float* __restrict__ W,
                                                       const float* __restrict__ b,
                                                       const float* __restrict__ dis,
                                                       float* __restrict__ Xn, int n) {
    constexpr int KQ = K / 4;
    __shared__ __align__(16) float4 Al[64 * KQ];
    int tid = threadIdx.x;
    int i0 = blockIdx.x * 64;
    for (int idx = tid; idx < 64 * KQ; idx += 192) {
        int gi = i0 + idx / KQ;
        Al[idx] = (gi < n) ? ((const float4*)A)[(size_t)i0 * KQ + idx]
                           : make_float4(0.f, 0.f, 0.f, 0.f);
    }
    __syncthreads();
    int fq = tid % 24;  // output float4 column
    int g = tid / 24;   // row group: rows g*8 .. g*8+7
    const float4* W4 = (const float4*)W;  // W4[k*24 + fq]
    float4 bb = ((const float4*)b)[fq];
    float4 acc[8];
#pragma unroll
    for (int r = 0; r < 8; ++r) acc[r] = bb;
    for (int kc = 0; kc < K; kc += 8) {
        float4 w[8];
#pragma unroll
        for (int kk = 0; kk < 8; ++kk) w[kk] = W4[(size_t)(kc + kk) * 24 + fq];
#pragma unroll
        for (int r = 0; r < 8; ++r) {
            const float4* ar = &Al[(g * 8 + r) * KQ + (kc >> 2)];
#pragma unroll
            for (int k4 = 0; k4 < 2; ++k4) {
                float4 a = ar[k4];
                float4 w0 = w[4 * k4 + 0], w1 = w[4 * k4 + 1];
                float4 w2 = w[4 * k4 + 2], w3 = w[4 * k4 + 3];
                acc[r].x += a.x * w0.x + a.y * w1.x + a.z * w2.x + a.w * w3.x;
                acc[r].y += a.x * w0.y + a.y * w1.y + a.z * w2.y + a.w * w3.y;
                acc[r].z += a.x * w0.z + a.y * w1.z + a.z * w2.z + a.w * w3.z;
                acc[r].w += a.x * w0.w + a.y * w1.w + a.z * w2.w + a.w * w3.w;
            }
        }
    }
#pragma unroll
    for (int r = 0; r < 8; ++r) {
        int gi = i0 + g * 8 + r;
        if (gi < n) {
            float4 o;
            o.x = LEAKY(acc[r].x); o.y = LEAKY(acc[r].y);
            o.z = LEAKY(acc[r].z); o.w = LEAKY(acc[r].w);
            if (SCALE) {
                float di = dis[gi];
                o.x *= di; o.y *= di; o.z *= di; o.w *= di;
            }
            ((float4*)Xn)[(size_t)gi * 24 + fq] = o;
        }
    }
}

__device__ __forceinline__ int lower_bound(const int* b, int n, int v) {
    int lo = 0, hi = n;
    while (lo < hi) {
        int m = (lo + hi) >> 1;
        if (b[m] < v) lo = m + 1; else hi = m;
    }
    return lo;
}

// grid = G*8, block = 96. Chunked per-graph partial max/sum.
__global__ void pool_partial(const float* __restrict__ X, const int* __restrict__ batch,
                             float* __restrict__ pmax, float* __restrict__ psum, int n) {
    int g = blockIdx.x / 8, ch = blockIdx.x % 8;
    int f = threadIdx.x;
    int s = lower_bound(batch, n, g), e = lower_bound(batch, n, g + 1);
    int len = e - s;
    int cs = s + (int)((long)len * ch / 8);
    int ce = s + (int)((long)len * (ch + 1) / 8);
    float mx = -INFINITY, sm = 0.f;
    for (int i = cs; i < ce; ++i) {
        float v = X[(size_t)i * 96 + f];
        mx = fmaxf(mx, v);
        sm += v;
    }
    pmax[(size_t)blockIdx.x * 96 + f] = mx;
    psum[(size_t)blockIdx.x * 96 + f] = sm;
}

__global__ void pool_reduce(const float* __restrict__ pmax, const float* __restrict__ psum,
                            const int* __restrict__ batch, float* __restrict__ pooled, int n) {
    int g = blockIdx.x, f = threadIdx.x;
    float mx = -INFINITY, sm = 0.f;
    for (int c = 0; c < 8; ++c) {
        mx = fmaxf(mx, pmax[(size_t)(g * 8 + c) * 96 + f]);
        sm += psum[(size_t)(g * 8 + c) * 96 + f];
    }
    int s = lower_bound(batch, n, g), e = lower_bound(batch, n, g + 1);
    float cnt = fmaxf((float)(e - s), 1.f);
    pooled[g * 192 + f] = mx;
    pooled[g * 192 + 96 + f] = sm / cnt;
}

// out[g] = leaky(pooled[g]@Wo1 + bo1) @ Wo2 + bo2
__global__ void mlp_kernel(const float* __restrict__ pooled, const float* __restrict__ Wo1,
                           const float* __restrict__ bo1, const float* __restrict__ Wo2,
                           const float* __restrict__ bo2, float* __restrict__ out) {
    __shared__ float sh[96];
    int g = blockIdx.x, f = threadIdx.x;
    float acc = bo1[f];
    for (int k = 0; k < 192; ++k) acc += pooled[g * 192 + k] * Wo1[k * 96 + f];
    float a = LEAKY(acc);
    sh[f] = a * Wo2[f];
    __syncthreads();
    if (f == 0) {
        float sacc = 0.f;
        for (int k = 0; k < 96; ++k) sacc += sh[k];
        out[g] = sacc + bo2[0];
    }
}

extern "C" void kernel_launch(void* const* d_in, const int* in_sizes, int n_in,
                              void* d_out, int out_size, void* d_ws, size_t ws_size,
                              hipStream_t stream) {
    const float* x      = (const float*)d_in[0];
    const int*   eidx   = (const int*)d_in[1];
    const int*   batch  = (const int*)d_in[2];
    const float* W_init = (const float*)d_in[3];
    const float* b_init = (const float*)d_in[4];
    const float* W1 = (const float*)d_in[5];  const float* b1 = (const float*)d_in[6];
    const float* W2 = (const float*)d_in[7];  const float* b2 = (const float*)d_in[8];
    const float* W3 = (const float*)d_in[9];  const float* b3 = (const float*)d_in[10];
    const float* W4 = (const float*)d_in[11]; const float* b4 = (const float*)d_in[12];
    const float* Wo1 = (const float*)d_in[13]; const float* bo1 = (const float*)d_in[14];
    const float* Wo2 = (const float*)d_in[15]; const float* bo2 = (const float*)d_in[16];
    float* out = (float*)d_out;

    const int N = in_sizes[2];
    const int E = in_sizes[1] / 2;
    const int G = out_size;
    const int* src = eidx;
    const int* dst = eidx + E;

    char* ws = (char*)d_ws;
    size_t off = 0;
    auto alloc = [&](size_t bytes) {
        size_t o = off;
        off += (bytes + 255) & ~(size_t)255;
        return o;
    };
    float* dis       = (float*)(ws + alloc((size_t)N * 4));
    int*   counts    = (int*)(ws + alloc((size_t)N * 4));
    int*   row_ptr   = (int*)(ws + alloc((size_t)(N + 1) * 4));
    int*   cursor    = (int*)(ws + alloc((size_t)N * 4));
    int*   bsum      = (int*)(ws + alloc(64 * 4));
    int*   bkt_cur   = (int*)(ws + alloc(NBMAX * 4));
    int*   edge_src  = (int*)(ws + alloc((size_t)E * 4));
    float* Z0        = (float*)(ws + alloc((size_t)N * 16 * 4));
    float* ZA        = (float*)(ws + alloc((size_t)N * 96 * 4));
    float* ZB        = (float*)(ws + alloc((size_t)N * 96 * 4));
    float* Agg       = (float*)(ws + alloc((size_t)N * 96 * 4));
    float* pmax      = (float*)(ws + alloc((size_t)G * 8 * 96 * 4));
    float* psum      = (float*)(ws + alloc((size_t)G * 8 * 96 * 4));
    float* pooled    = (float*)(ws + alloc((size_t)G * 192 * 4));
    uint2* tmp       = (uint2*)Agg;  // disjoint lifetime: bin/place finish before agg0
    (void)ws_size; (void)n_in;

    const int nbScan = (N + 2047) / 2048;
    const int nbBkt  = (N + (1 << BK_SHIFT) - 1) >> BK_SHIFT;
    const int nbWave = (N + 3) / 4;       // 4 nodes (waves) per 256-thread block
    const int nbTile = (N + 63) / 64;

    zero_i32<<<(N + 255) / 256, 256, 0, stream>>>(counts, N);
    count_kernel<<<(E + 255) / 256, 256, 0, stream>>>(dst, counts, E);
    scanA<<<nbScan, 256, 0, stream>>>(counts, row_ptr, bsum, dis, N);
    scanB<<<1, 64, 0, stream>>>(bsum, nbScan);
    scanC<<<(N + 255) / 256, 256, 0, stream>>>(row_ptr, cursor, bkt_cur, bsum, N, E);
    bin_kernel<<<(E + 2047) / 2048, 256, 0, stream>>>(src, dst, bkt_cur, tmp, E, nbBkt);
    place_kernel<<<nbBkt, 512, 0, stream>>>(tmp, row_ptr, cursor, edge_src, N);
    scale_kernel<<<(N * 4 + 255) / 256, 256, 0, stream>>>(x, dis, Z0, N * 4, 4);

    // Layer 0: aggregate pre-scaled 16-wide input, then 16x96 GEMM (-> Z1).
    agg_wave<4, 1, 2><<<nbWave, 256, 0, stream>>>(Z0, dis, row_ptr, edge_src, Agg, N);
    gemm_act_kernel<16, true><<<nbTile, 192, 0, stream>>>(Agg, W_init, b_init, dis, ZA, N);

    const float* Ws[4] = {W1, W2, W3, W4};
    const float* bs[4] = {b1, b2, b3, b4};
    float* cur = ZA;
    float* nxt = ZB;
    for (int l = 0; l < 4; ++l) {
        agg_wave<8, 3, 4><<<nbWave, 256, 0, stream>>>(cur, dis, row_ptr, edge_src, Agg, N);
        if (l < 3)
            gemm_act_kernel<96, true><<<nbTile, 192, 0, stream>>>(Agg, Ws[l], bs[l], dis, nxt, N);
        else  // last layer: pooling needs the unscaled activation H
            gemm_act_kernel<96, false><<<nbTile, 192, 0, stream>>>(Agg, Ws[l], bs[l], dis, nxt, N);
        float* t = cur; cur = nxt; nxt = t;
    }

    pool_partial<<<G * 8, 96, 0, stream>>>(cur, batch, pmax, psum, N);
    pool_reduce<<<G, 96, 0, stream>>>(pmax, psum, batch, pooled, N);
    mlp_kernel<<<G, 96, 0, stream>>>(pooled, Wo1, bo1, Wo2, bo2, out);
}